// Round 12
// baseline (314.797 us; speedup 1.0000x reference)
//
#include <hip/hip_runtime.h>

typedef __bf16 bf16;
typedef __bf16 bf16x8 __attribute__((ext_vector_type(8)));
typedef __bf16 bf16x4 __attribute__((ext_vector_type(4)));
typedef __bf16 bf16x2 __attribute__((ext_vector_type(2)));
typedef float f32x4 __attribute__((ext_vector_type(4)));
typedef float f32x16 __attribute__((ext_vector_type(16)));
typedef unsigned u32;
typedef unsigned u32x4v __attribute__((ext_vector_type(4)));

static constexpr int Hh = 8;    // query heads
static constexpr int Dd = 256;  // head dim
static constexpr int Ss = 2048; // seq len
static constexpr int Cc = 2048; // hidden
static constexpr int NS = 4096; // merged batch*seq

typedef const __attribute__((address_space(1))) unsigned int as1_u32;
typedef __attribute__((address_space(3))) unsigned int as3_u32;

// async global->LDS, 16B per lane; lds dest is wave-uniform base + lane*16
__device__ __forceinline__ void gl_lds16(const void* g, void* l) {
  __builtin_amdgcn_global_load_lds((as1_u32*)(unsigned long long)g,
                                   (as3_u32*)(unsigned int)(unsigned long long)l,
                                   16, 0, 0);
}

__device__ __forceinline__ f32x4 mfma16(bf16x8 a, bf16x8 b, f32x4 c) {
  return __builtin_amdgcn_mfma_f32_16x16x32_bf16(a, b, c, 0, 0, 0);
}
__device__ __forceinline__ f32x16 mfma32(bf16x8 a, bf16x8 b, f32x16 c) {
  return __builtin_amdgcn_mfma_f32_32x32x16_bf16(a, b, c, 0, 0, 0);
}

__device__ __forceinline__ u32 pk_bf16(float lo, float hi) {
  bf16x2 t;
  t[0] = (bf16)lo;
  t[1] = (bf16)hi;
  return __builtin_bit_cast(u32, t);
}

// ---------------- elementwise f32 -> bf16 ----------------
__global__ __launch_bounds__(256) void cvt_w(const float* __restrict__ in,
                                             bf16* __restrict__ out, int n) {
  int i = (blockIdx.x * 256 + threadIdx.x) * 4;
  if (i >= n) return;
  const float4 v = *(const float4*)(in + i);
  bf16x4 o;
  o[0] = (bf16)v.x; o[1] = (bf16)v.y; o[2] = (bf16)v.z; o[3] = (bf16)v.w;
  *(bf16x4*)(out + i) = o;
}

// ---------------- [B][R][S] f32 -> [B][S][R] bf16 ----------------
__global__ __launch_bounds__(256) void transpose_cvt(const float* __restrict__ in,
                                                     bf16* __restrict__ out,
                                                     int R, int S) {
  __shared__ float t[32][33];
  const int b = blockIdx.z;
  const long base = (long)b * R * S;
  const int s0 = blockIdx.x * 32, r0 = blockIdx.y * 32;
  const int tx = threadIdx.x, ty = threadIdx.y;
#pragma unroll
  for (int i = 0; i < 32; i += 8)
    t[ty + i][tx] = in[base + (long)(r0 + ty + i) * S + s0 + tx];
  __syncthreads();
#pragma unroll
  for (int i = 0; i < 32; i += 8)
    out[base + (long)(s0 + ty + i) * R + r0 + tx] = (bf16)t[tx][ty + i];
}

// ---------------- 4x fused [B][128][S] f32 -> [B][S][128] bf16 -------------
__global__ __launch_bounds__(256) void transpose_cvt4(
    const float* __restrict__ s0, const float* __restrict__ s1,
    const float* __restrict__ s2, const float* __restrict__ s3,
    bf16* __restrict__ d0, bf16* __restrict__ d1, bf16* __restrict__ d2,
    bf16* __restrict__ d3, int R, int S) {
  __shared__ float t[32][33];
  const int arr = blockIdx.y >> 2;
  const int r0 = (blockIdx.y & 3) * 32;
  const float* in = (arr == 0) ? s0 : (arr == 1) ? s1 : (arr == 2) ? s2 : s3;
  bf16* out = (arr == 0) ? d0 : (arr == 1) ? d1 : (arr == 2) ? d2 : d3;
  const int b = blockIdx.z;
  const long base = (long)b * R * S;
  const int s0i = blockIdx.x * 32;
  const int tx = threadIdx.x, ty = threadIdx.y;
#pragma unroll
  for (int i = 0; i < 32; i += 8)
    t[ty + i][tx] = in[base + (long)(r0 + ty + i) * S + s0i + tx];
  __syncthreads();
#pragma unroll
  for (int i = 0; i < 32; i += 8)
    out[base + (long)(s0i + ty + i) * R + r0 + tx] = (bf16)t[tx][ty + i];
}

// ---------------- RoPE + transpose: [o-rows][NS cols] -> [B][nH][S][256] ---
__global__ __launch_bounds__(256) void rope_transpose(
    const bf16* __restrict__ xin, const bf16* __restrict__ sint,
    const bf16* __restrict__ cost, bf16* __restrict__ xout, int nH,
    long bOff, long rowStr) {
  __shared__ __align__(16) bf16 ti[32][264];  // [s][d], padded
  const int b = blockIdx.z, h = blockIdx.y, s0 = blockIdx.x * 32;
  const int tx = threadIdx.x, ty = threadIdx.y;
  const bf16* src = xin + b * bOff + (long)h * Dd * rowStr + s0;
#pragma unroll
  for (int i = 0; i < 32; ++i) {
    int d = ty + i * 8;
    ti[tx][d] = src[(long)d * rowStr + tx];
  }
  __syncthreads();
  const int t = ty * 32 + tx;
  const int s = t >> 3;
  const int dpart = t & 7;
  const bf16* sp = sint + ((long)b * Ss + s0 + s) * 128;
  const bf16* cp = cost + ((long)b * Ss + s0 + s) * 128;
  bf16* dst = xout + (((long)(b * nH + h)) * Ss + s0 + s) * Dd;
#pragma unroll
  for (int i = 0; i < 4; ++i) {
    int d0 = dpart * 8 + i * 64;
    int dh = d0 & 127;
    bf16x8 a = *(const bf16x8*)&ti[s][d0];
    bf16x8 p = *(const bf16x8*)&ti[s][(d0 < 128) ? d0 + 128 : d0 - 128];
    bf16x8 sn = *(const bf16x8*)&sp[dh];
    bf16x8 cs = *(const bf16x8*)&cp[dh];
    bf16x8 o;
#pragma unroll
    for (int j = 0; j < 8; ++j) {
      float av = (float)a[j], pv = (float)p[j];
      float c = (float)cs[j], sv = (float)sn[j];
      float val = (d0 < 128) ? (av * c - pv * sv) : (av * c + pv * sv);
      o[j] = (bf16)val;
    }
    *(bf16x8*)&dst[d0] = o;
  }
}

// ---------------- GEMM 128x128: C[o][n] = sum_c A[o][c] * Bt[n][c] ---------
__global__ __launch_bounds__(256, 2) void gemm_bt(
    const bf16* __restrict__ A, const bf16* __restrict__ Bt,
    bf16* __restrict__ Cb, float* __restrict__ Cf, int M, int N, int K,
    int ntiles) {
  __shared__ __align__(16) bf16 lA[2][128 * 64];
  __shared__ __align__(16) bf16 lB[2][128 * 64];
  const int nwg = gridDim.x;
  const int cpx = nwg >> 3;                       // nwg % 8 == 0 always here
  const int bid2 = (blockIdx.x & 7) * cpx + (blockIdx.x >> 3);
  const int mt = (bid2 / ntiles) * 128, nt = (bid2 % ntiles) * 128;
  const int tid = threadIdx.x;
  const int wid = tid >> 6, lane = tid & 63;
  const int g = lane >> 4, r = lane & 15;
  const int wr = wid >> 1, wc = wid & 1;

  auto stage = [&](int buf, int kt) {
#pragma unroll
    for (int it = 0; it < 4; ++it) {
      int off = it * 4096 + tid * 16;
      int row = off >> 7;              // 128B rows (64 bf16)
      int c = (off >> 4) & 7;
      int csw = c ^ (row & 7);
      gl_lds16((const char*)(A + (long)(mt + row) * K + kt) + csw * 16,
               (char*)lA[buf] + it * 4096 + wid * 1024);
      gl_lds16((const char*)(Bt + (long)(nt + row) * K + kt) + csw * 16,
               (char*)lB[buf] + it * 4096 + wid * 1024);
    }
  };

  const f32x4 zf = {0.f, 0.f, 0.f, 0.f};
  f32x4 acc[4][4];
#pragma unroll
  for (int m = 0; m < 4; ++m)
#pragma unroll
    for (int n = 0; n < 4; ++n) acc[m][n] = zf;

  stage(0, 0);
  __syncthreads();
  int cur = 0;
  for (int kt = 0; kt < K; kt += 64) {
    if (kt + 64 < K) stage(cur ^ 1, kt + 64);
#pragma unroll
    for (int kk = 0; kk < 2; ++kk) {
      bf16x8 af[4], bfv[4];
#pragma unroll
      for (int m = 0; m < 4; ++m) {
        int row = wr * 64 + m * 16 + r;
        int csw = (kk * 4 + g) ^ (row & 7);
        af[m] = *(const bf16x8*)((const char*)lA[cur] + row * 128 + csw * 16);
      }
#pragma unroll
      for (int n = 0; n < 4; ++n) {
        int row = wc * 64 + n * 16 + r;
        int csw = (kk * 4 + g) ^ (row & 7);
        bfv[n] = *(const bf16x8*)((const char*)lB[cur] + row * 128 + csw * 16);
      }
#pragma unroll
      for (int m = 0; m < 4; ++m)
#pragma unroll
        for (int n = 0; n < 4; ++n)
          acc[m][n] = mfma16(af[m], bfv[n], acc[m][n]);
    }
    __syncthreads();
    cur ^= 1;
  }

#pragma unroll
  for (int m = 0; m < 4; ++m)
#pragma unroll
    for (int n = 0; n < 4; ++n)
#pragma unroll
      for (int e = 0; e < 4; ++e) {
        int orow = mt + wr * 64 + m * 16 + g * 4 + e;
        int col = nt + wc * 64 + n * 16 + r;
        if (Cf) {
          // out f32 [B][M][2048]: col = b*2048 + s
          long idx = (long)(col >> 11) * ((long)Cc * Ss) + (long)orow * Ss +
                     (col & 2047);
          Cf[idx] = acc[m][n][e];
        } else {
          Cb[(long)orow * N + col] = (bf16)acc[m][n][e];
        }
      }
}

// ---------------- GEMM 64x128 (small-M / KV projection) --------------------
__global__ __launch_bounds__(256, 3) void gemm_bt64(
    const bf16* __restrict__ A, const bf16* __restrict__ Bt,
    bf16* __restrict__ Cb, int M, int N, int K, int ntiles) {
  __shared__ __align__(16) bf16 lA[2][64 * 64];
  __shared__ __align__(16) bf16 lB[2][128 * 64];
  const int nwg = gridDim.x;
  const int cpx = nwg >> 3;
  const int bid2 = (blockIdx.x & 7) * cpx + (blockIdx.x >> 3);
  const int mt = (bid2 / ntiles) * 64, nt = (bid2 % ntiles) * 128;
  const int tid = threadIdx.x;
  const int wid = tid >> 6, lane = tid & 63;
  const int g = lane >> 4, r = lane & 15;
  const int wn = wid;

  auto stage = [&](int buf, int kt) {
#pragma unroll
    for (int it = 0; it < 2; ++it) {   // A tile 64x64 = 8KB
      int off = it * 4096 + tid * 16;
      int row = off >> 7;
      int c = (off >> 4) & 7;
      int csw = c ^ (row & 7);
      gl_lds16((const char*)(A + (long)(mt + row) * K + kt) + csw * 16,
               (char*)lA[buf] + it * 4096 + wid * 1024);
    }
#pragma unroll
    for (int it = 0; it < 4; ++it) {   // B tile 128x64 = 16KB
      int off = it * 4096 + tid * 16;
      int row = off >> 7;
      int c = (off >> 4) & 7;
      int csw = c ^ (row & 7);
      gl_lds16((const char*)(Bt + (long)(nt + row) * K + kt) + csw * 16,
               (char*)lB[buf] + it * 4096 + wid * 1024);
    }
  };

  const f32x4 zf = {0.f, 0.f, 0.f, 0.f};
  f32x4 acc[4][2];
#pragma unroll
  for (int m = 0; m < 4; ++m)
#pragma unroll
    for (int n = 0; n < 2; ++n) acc[m][n] = zf;

  stage(0, 0);
  __syncthreads();
  int cur = 0;
  for (int kt = 0; kt < K; kt += 64) {
    if (kt + 64 < K) stage(cur ^ 1, kt + 64);
#pragma unroll
    for (int kk = 0; kk < 2; ++kk) {
      bf16x8 af[4], bfv[2];
#pragma unroll
      for (int m = 0; m < 4; ++m) {
        int row = m * 16 + r;
        int csw = (kk * 4 + g) ^ (row & 7);
        af[m] = *(const bf16x8*)((const char*)lA[cur] + row * 128 + csw * 16);
      }
#pragma unroll
      for (int n = 0; n < 2; ++n) {
        int row = wn * 32 + n * 16 + r;
        int csw = (kk * 4 + g) ^ (row & 7);
        bfv[n] = *(const bf16x8*)((const char*)lB[cur] + row * 128 + csw * 16);
      }
#pragma unroll
      for (int m = 0; m < 4; ++m)
#pragma unroll
        for (int n = 0; n < 2; ++n)
          acc[m][n] = mfma16(af[m], bfv[n], acc[m][n]);
    }
    __syncthreads();
    cur ^= 1;
  }

#pragma unroll
  for (int m = 0; m < 4; ++m)
#pragma unroll
    for (int n = 0; n < 2; ++n)
#pragma unroll
      for (int e = 0; e < 4; ++e) {
        int orow = mt + m * 16 + g * 4 + e;
        int col = nt + wn * 32 + n * 16 + r;
        Cb[(long)orow * N + col] = (bf16)acc[m][n][e];
      }
}

// ---------------- flash attention: 32x32 MFMA, split-KV across blocks ------
// Per-wave compute verbatim from R5 (verified passing, absmax 6.1e-4).
// Defenses vs R6 failure: NORMALIZED partials (bf16 rel err = same as the
// passing R8 path), EXACT running max (no defer-max), ml in dead ws zone.
// qr: [B][H][S][256], kr: [B][S][256], kv: [512][NS] (V rows 256..511,
// cols n = b*2048+s), mask: [B][1][S][S]
// opart: [B][2kvh][H][S][256] bf16 normalized O; ml: [B][2kvh][H][S] (m,l)
__global__ __launch_bounds__(256, 2) void attn_split(
    const bf16* __restrict__ qr, const bf16* __restrict__ kr,
    const bf16* __restrict__ kv, const float* __restrict__ mask,
    bf16* __restrict__ opart, float2* __restrict__ ml) {
  __shared__ __align__(16) bf16 lK[2][32 * 256];  // [ks][d], chunk^(row&7)
  __shared__ __align__(16) bf16 lV[2][256 * 32];  // [d][ks], chunk^((row>>1)&3)
  const int i = blockIdx.x;
  const int flat = (i & 7) * 64 + (i >> 3);       // XCD-aware
  const int b = flat >> 8;
  const int rem = flat & 255;
  const int kvh = rem >> 7;
  const int hg = (rem >> 6) & 1;
  const int q0 = (rem & 63) * 32;
  const int tid = threadIdx.x;
  const int wid = tid >> 6, lane = tid & 63;
  const int l31 = lane & 31, hi = lane >> 5;
  const int h = hg * 4 + wid;

  // Q B-frags: lane holds Q[q0+l31][kk*16 + hi*8 + j]
  bf16x8 qf[16];
  const bf16* qp = qr + (((long)(b * Hh + h)) * Ss + q0 + l31) * Dd;
#pragma unroll
  for (int kk = 0; kk < 16; ++kk)
    qf[kk] = *(const bf16x8*)&qp[kk * 16 + hi * 8];

  f32x16 oacc[8] = {};
  float mrun = -3e38f, lrun = 0.f;

  const char* kb = (const char*)(kr + (long)b * Ss * Dd);
  // V row d lives at kv[(256+d)*NS + b*2048 + s]
  const char* vb = (const char*)(kv + (long)256 * NS + (long)b * Ss);
  const float* mb = mask + (long)b * Ss * Ss;

  auto stage = [&](int buf, int kt) {
    const char* gK = kb + (long)kt * 512;
#pragma unroll
    for (int it = 0; it < 4; ++it) {
      int off = it * 4096 + tid * 16;
      int row = off >> 9;               // 512B rows
      int c = (off >> 4) & 31;
      int csw = c ^ (row & 7);
      gl_lds16(gK + row * 512 + csw * 16,
               (char*)lK[buf] + it * 4096 + wid * 1024);
    }
#pragma unroll
    for (int it = 0; it < 4; ++it) {
      int off = it * 4096 + tid * 16;
      int row = off >> 6;               // 64B rows
      int c = (off >> 4) & 3;
      int csw = c ^ ((row >> 1) & 3);
      gl_lds16(vb + (long)row * (NS * 2) + (long)kt * 2 + csw * 16,
               (char*)lV[buf] + it * 4096 + wid * 1024);
    }
  };

  const int kbeg = kvh * (Ss / 2), kend = kbeg + (Ss / 2);
  stage(0, kbeg);
  __syncthreads();
  int cur = 0;

  for (int kt = kbeg; kt < kend; kt += 32) {
    if (kt + 32 < kend) stage(cur ^ 1, kt + 32);

    // mask: reg r covers ks-col = kt + (r>>2)*8 + hi*4 + (r&3)
    const float* mrow = mb + (long)(q0 + l31) * Ss + kt;
    float4 mv[4];
#pragma unroll
    for (int grp = 0; grp < 4; ++grp)
      mv[grp] = *(const float4*)(mrow + grp * 8 + hi * 4);

    // QK^T: A = K[ks=l31][kk*16+hi*8+j], B = Q -> D[ks][q=l31]
    f32x16 sacc = {};
    __builtin_amdgcn_s_setprio(1);
#pragma unroll
    for (int kk = 0; kk < 16; ++kk) {
      int csw = (kk * 2 + hi) ^ (l31 & 7);
      bf16x8 kf = *(const bf16x8*)((const char*)lK[cur] + l31 * 512 + csw * 16);
      sacc = mfma32(kf, qf[kk], sacc);
    }
    __builtin_amdgcn_s_setprio(0);

    // in-register row softmax, EXACT running max (no defer)
    float x[16];
#pragma unroll
    for (int r = 0; r < 16; ++r)
      x[r] = sacc[r] * 0.0625f + ((const float*)&mv[r >> 2])[r & 3];
    float mx = fmaxf(
        fmaxf(fmaxf(fmaxf(x[0], x[1]), fmaxf(x[2], x[3])),
              fmaxf(fmaxf(x[4], x[5]), fmaxf(x[6], x[7]))),
        fmaxf(fmaxf(fmaxf(x[8], x[9]), fmaxf(x[10], x[11])),
              fmaxf(fmaxf(x[12], x[13]), fmaxf(x[14], x[15]))));
    mx = fmaxf(mx, __shfl_xor(mx, 32, 64));
    const float mnew = fmaxf(mrun, mx);
    const float al = __expf(mrun - mnew);  // first iter: exp(-inf)=0
    mrun = mnew;
    float p[16];
#pragma unroll
    for (int r = 0; r < 16; ++r) p[r] = __expf(x[r] - mrun);
    float rs = ((p[0] + p[1]) + (p[2] + p[3])) +
               ((p[4] + p[5]) + (p[6] + p[7])) +
               ((p[8] + p[9]) + (p[10] + p[11])) +
               ((p[12] + p[13]) + (p[14] + p[15]));
    rs += __shfl_xor(rs, 32, 64);
    lrun = lrun * al + rs;
#pragma unroll
    for (int d = 0; d < 8; ++d) oacc[d] *= al;

    // P -> bf16 A-frags via pack + permlane32_swap (halves exchange)
    bf16x8 pf[2];
#pragma unroll
    for (int kk2 = 0; kk2 < 2; ++kk2) {
      u32 a0 = pk_bf16(p[kk2 * 8 + 0], p[kk2 * 8 + 1]);
      u32 a1 = pk_bf16(p[kk2 * 8 + 2], p[kk2 * 8 + 3]);
      u32 b0 = pk_bf16(p[kk2 * 8 + 4], p[kk2 * 8 + 5]);
      u32 b1 = pk_bf16(p[kk2 * 8 + 6], p[kk2 * 8 + 7]);
      asm("v_permlane32_swap_b32 %0, %1" : "+v"(a0), "+v"(b0));
      asm("v_permlane32_swap_b32 %0, %1" : "+v"(a1), "+v"(b1));
      u32x4v w;
      w[0] = a0; w[1] = a1; w[2] = b0; w[3] = b1;
      pf[kk2] = __builtin_bit_cast(bf16x8, w);
    }

    // PV: A = V[d=db*32+l31][ks], B = P -> D[d_local][q=l31]
    __builtin_amdgcn_s_setprio(1);
#pragma unroll
    for (int kk2 = 0; kk2 < 2; ++kk2) {
#pragma unroll
      for (int db = 0; db < 8; ++db) {
        int csw = (kk2 * 2 + hi) ^ ((l31 >> 1) & 3);
        bf16x8 vf = *(const bf16x8*)((const char*)lV[cur] +
                                     (db * 32 + l31) * 64 + csw * 16);
        oacc[db] = mfma32(vf, pf[kk2], oacc[db]);
      }
    }
    __builtin_amdgcn_s_setprio(0);

    __syncthreads();
    cur ^= 1;
  }

  // ---- write NORMALIZED partial O/l (bf16) + (m, l) f32 ----
  const float inv = 1.f / lrun;
  const long ridx = (((long)(b * 2 + kvh) * Hh + h)) * Ss + q0 + l31;
  bf16* po = opart + ridx * Dd;
#pragma unroll
  for (int db = 0; db < 8; ++db) {
#pragma unroll
    for (int grp = 0; grp < 4; ++grp) {
      bf16x4 o4;
#pragma unroll
      for (int e = 0; e < 4; ++e) o4[e] = (bf16)(oacc[db][grp * 4 + e] * inv);
      *(bf16x4*)&po[db * 32 + grp * 8 + hi * 4] = o4;
    }
  }
  if (hi == 0) {
    float2 v;
    v.x = mrun;
    v.y = lrun;
    ml[ridx] = v;
  }
}

// ---------------- merge the two KV-half partials (normalized) --------------
__global__ __launch_bounds__(256) void attn_merge(
    const bf16* __restrict__ opart, const float2* __restrict__ ml,
    bf16* __restrict__ attnb) {
  const long t = (long)blockIdx.x * 256 + threadIdx.x;  // 262144 threads
  const int d0 = (int)(t & 7) << 5;                     // 32-elem chunk
  const long R = t >> 3;                                // (b*H + h)*S + s
  const long b = R >> 14;
  const long rem = R & 16383;                           // h*2048 + s
  const int h = (int)(rem >> 11);
  const int s = (int)(rem & 2047);
  const long i0 = (b * 2 + 0) * ((long)Hh * Ss) + rem;
  const long i1 = (b * 2 + 1) * ((long)Hh * Ss) + rem;
  const float2 ml0 = ml[i0], ml1 = ml[i1];
  const float m = fmaxf(ml0.x, ml1.x);
  const float w0 = ml0.y * __expf(ml0.x - m);
  const float w1 = ml1.y * __expf(ml1.x - m);
  const float inv = 1.f / (w0 + w1);
  const float s0 = w0 * inv, s1 = w1 * inv;
  const bf16* p0 = opart + i0 * Dd + d0;
  const bf16* p1 = opart + i1 * Dd + d0;
  bf16* po = attnb + ((long)b * Ss + s) * (Hh * Dd) + h * Dd + d0;
#pragma unroll
  for (int j = 0; j < 4; ++j) {
    bf16x8 v0 = *(const bf16x8*)(p0 + j * 8);
    bf16x8 v1 = *(const bf16x8*)(p1 + j * 8);
    bf16x8 o;
#pragma unroll
    for (int e = 0; e < 8; ++e)
      o[e] = (bf16)((float)v0[e] * s0 + (float)v1[e] * s1);
    *(bf16x8*)(po + j * 8) = o;
  }
}

// ---------------- launcher -------------------------------------------------
extern "C" void kernel_launch(void* const* d_in, const int* in_sizes, int n_in,
                              void* d_out, int out_size, void* d_ws,
                              size_t ws_size, hipStream_t stream) {
  const float* Xq = (const float*)d_in[0];
  const float* Xkv = (const float*)d_in[1];
  const float* sin_q = (const float*)d_in[2];
  const float* cos_q = (const float*)d_in[3];
  const float* sin_k = (const float*)d_in[4];
  const float* cos_k = (const float*)d_in[5];
  const float* mask = (const float*)d_in[6];
  const float* Wq = (const float*)d_in[7];
  const float* Wk = (const float*)d_in[8];
  const float* Wv = (const float*)d_in[9];
  const float* Wo = (const float*)d_in[10];
  float* out = (float*)d_out;

  char* ws = (char*)d_ws;
  const size_t MB = 1u << 20;
  bf16* Wq_bf = (bf16*)(ws + 0 * MB);
  bf16* Wo_bf = (bf16*)(ws + 8 * MB);
  bf16* Wkv_bf = (bf16*)(ws + 16 * MB);  // K rows 0..255, V rows 256..511
  bf16* Wv_bf = (bf16*)(ws + 17 * MB);
  bf16* sin_qt = (bf16*)(ws + 18 * MB);
  bf16* cos_qt = (bf16*)(ws + 19 * MB);
  bf16* sin_kt = (bf16*)(ws + 20 * MB);
  bf16* cos_kt = (bf16*)(ws + 21 * MB);
  bf16* Xtq = (bf16*)(ws + 22 * MB);   // [4096][2048]; reused as qr
  bf16* Xtkv = (bf16*)(ws + 38 * MB);  // [4096][2048]; reused as kr
  // ml in the dead tail of Xtkv (40..54MB) — only KV-GEMM reads Xtkv,
  // finished before attention (placement verified harmless in R7).
  float2* ml = (float2*)(ws + 44 * MB); // [B][2][H][S] (1 MB)
  bf16* q_tmp = (bf16*)(ws + 54 * MB); // [2048][4096]; reused as attn out
  bf16* kv_tmp = (bf16*)(ws + 70 * MB); // [512][4096] fused K/V proj
  bf16* qr = (bf16*)(ws + 22 * MB);
  bf16* kr = (bf16*)(ws + 38 * MB);
  bf16* attnb = (bf16*)(ws + 54 * MB);
  bf16* opart = (bf16*)d_out;  // 32MiB scratch; Wo GEMM overwrites after

  dim3 b256(256), b32x8(32, 8);

  // weight converts (Wk, Wv into adjacent halves of Wkv)
  cvt_w<<<4096, b256, 0, stream>>>(Wq, Wq_bf, Cc * Cc);
  cvt_w<<<4096, b256, 0, stream>>>(Wo, Wo_bf, Cc * Cc);
  cvt_w<<<512, b256, 0, stream>>>(Wk, (bf16*)Wkv_bf, Dd * Cc);
  cvt_w<<<512, b256, 0, stream>>>(Wv, Wv_bf, Dd * Cc);

  // activations transposed to [S][*] bf16
  transpose_cvt<<<dim3(64, 64, 2), b32x8, 0, stream>>>(Xq, Xtq, Cc, Ss);
  transpose_cvt<<<dim3(64, 64, 2), b32x8, 0, stream>>>(Xkv, Xtkv, Cc, Ss);
  // all 4 sin/cos transposes in one launch
  transpose_cvt4<<<dim3(64, 16, 2), b32x8, 0, stream>>>(
      sin_q, cos_q, sin_k, cos_k, sin_qt, cos_qt, sin_kt, cos_kt, 128, Ss);

  // projections over merged N = B*S = 4096 (Bt rows are batch-contiguous)
  gemm_bt<<<dim3(512), b256, 0, stream>>>(Wq_bf, Xtq, q_tmp, nullptr,
                                          Cc, NS, Cc, NS / 128);
  gemm_bt64<<<dim3(256), b256, 0, stream>>>(Wkv_bf, Xtkv, kv_tmp,
                                            2 * Dd, NS, Cc, NS / 128);

  // RoPE + layout change (intermediate layout: rows o, cols n = b*2048+s)
  rope_transpose<<<dim3(64, 8, 2), b32x8, 0, stream>>>(
      q_tmp, sin_qt, cos_qt, qr, Hh, (long)Ss, (long)NS);
  rope_transpose<<<dim3(64, 1, 2), b32x8, 0, stream>>>(
      kv_tmp, sin_kt, cos_kt, kr, 1, (long)Ss, (long)NS);

  // attention: 512 blocks (2/CU), 4 waves = 4 heads, 32 q-rows, one KV half;
  // normalized partials to opart/ml, then merge
  attn_split<<<dim3(512), b256, 0, stream>>>(qr, kr, kv_tmp, mask, opart, ml);
  attn_merge<<<dim3(1024), b256, 0, stream>>>(opart, ml, attnb);

  // output projection (f32 out, remapped to [B][hidden][S])
  gemm_bt<<<dim3(512), b256, 0, stream>>>(Wo_bf, attnb, nullptr, out,
                                          Cc, NS, Cc, NS / 128);
}

// Round 13
// 261.850 us; speedup vs baseline: 1.2022x; 1.2022x over previous
//
#include <hip/hip_runtime.h>

typedef __bf16 bf16;
typedef __bf16 bf16x8 __attribute__((ext_vector_type(8)));
typedef __bf16 bf16x4 __attribute__((ext_vector_type(4)));
typedef float f32x4 __attribute__((ext_vector_type(4)));

static constexpr int Hh = 8;    // query heads
static constexpr int Dd = 256;  // head dim
static constexpr int Ss = 2048; // seq len
static constexpr int Cc = 2048; // hidden
static constexpr int NS = 4096; // merged batch*seq

typedef const __attribute__((address_space(1))) unsigned int as1_u32;
typedef __attribute__((address_space(3))) unsigned int as3_u32;

// async global->LDS, 16B per lane; lds dest is wave-uniform base + lane*16
__device__ __forceinline__ void gl_lds16(const void* g, void* l) {
  __builtin_amdgcn_global_load_lds((as1_u32*)(unsigned long long)g,
                                   (as3_u32*)(unsigned int)(unsigned long long)l,
                                   16, 0, 0);
}

__device__ __forceinline__ f32x4 mfma16(bf16x8 a, bf16x8 b, f32x4 c) {
  return __builtin_amdgcn_mfma_f32_16x16x32_bf16(a, b, c, 0, 0, 0);
}

// ---------------- all weight converts in ONE launch ----------------
// blocks [0,4096): Wq->Wq_bf; [4096,8192): Wo->Wo_bf;
// [8192,8704): Wk->Wkv_bf[0:]; [8704,9216): Wv->Wkv_bf[Dd*Cc:]
__global__ __launch_bounds__(256) void cvt_all(
    const float* __restrict__ Wq, const float* __restrict__ Wo,
    const float* __restrict__ Wk, const float* __restrict__ Wv,
    bf16* __restrict__ Wq_bf, bf16* __restrict__ Wo_bf,
    bf16* __restrict__ Wkv_bf) {
  const int blk = blockIdx.x;
  const float* in;
  bf16* out;
  int base;
  if (blk < 4096) {
    in = Wq; out = Wq_bf; base = blk;
  } else if (blk < 8192) {
    in = Wo; out = Wo_bf; base = blk - 4096;
  } else if (blk < 8704) {
    in = Wk; out = Wkv_bf; base = blk - 8192;
  } else {
    in = Wv; out = Wkv_bf + (long)Dd * Cc; base = blk - 8704;
  }
  int i = (base * 256 + threadIdx.x) * 4;
  const float4 v = *(const float4*)(in + i);
  bf16x4 o;
  o[0] = (bf16)v.x; o[1] = (bf16)v.y; o[2] = (bf16)v.z; o[3] = (bf16)v.w;
  *(bf16x4*)(out + i) = o;
}

// ---------------- [B][R][S] f32 -> [B][S][R] bf16 ----------------
__global__ __launch_bounds__(256) void transpose_cvt(const float* __restrict__ in,
                                                     bf16* __restrict__ out,
                                                     int R, int S) {
  __shared__ float t[32][33];
  const int b = blockIdx.z;
  const long base = (long)b * R * S;
  const int s0 = blockIdx.x * 32, r0 = blockIdx.y * 32;
  const int tx = threadIdx.x, ty = threadIdx.y;
#pragma unroll
  for (int i = 0; i < 32; i += 8)
    t[ty + i][tx] = in[base + (long)(r0 + ty + i) * S + s0 + tx];
  __syncthreads();
#pragma unroll
  for (int i = 0; i < 32; i += 8)
    out[base + (long)(s0 + ty + i) * R + r0 + tx] = (bf16)t[tx][ty + i];
}

// ---------------- 4x fused [B][128][S] f32 -> [B][S][128] bf16 -------------
__global__ __launch_bounds__(256) void transpose_cvt4(
    const float* __restrict__ s0, const float* __restrict__ s1,
    const float* __restrict__ s2, const float* __restrict__ s3,
    bf16* __restrict__ d0, bf16* __restrict__ d1, bf16* __restrict__ d2,
    bf16* __restrict__ d3, int R, int S) {
  __shared__ float t[32][33];
  const int arr = blockIdx.y >> 2;
  const int r0 = (blockIdx.y & 3) * 32;
  const float* in = (arr == 0) ? s0 : (arr == 1) ? s1 : (arr == 2) ? s2 : s3;
  bf16* out = (arr == 0) ? d0 : (arr == 1) ? d1 : (arr == 2) ? d2 : d3;
  const int b = blockIdx.z;
  const long base = (long)b * R * S;
  const int s0i = blockIdx.x * 32;
  const int tx = threadIdx.x, ty = threadIdx.y;
#pragma unroll
  for (int i = 0; i < 32; i += 8)
    t[ty + i][tx] = in[base + (long)(r0 + ty + i) * S + s0i + tx];
  __syncthreads();
#pragma unroll
  for (int i = 0; i < 32; i += 8)
    out[base + (long)(s0i + ty + i) * R + r0 + tx] = (bf16)t[tx][ty + i];
}

// ---------------- RoPE + transpose (Q heads and K in ONE launch) -----------
// blockIdx.y < 8: head y of q_tmp -> qr.  blockIdx.y == 8: K of kv_tmp -> kr.
// Intermediate layout: rows o, cols n = b*2048+s (row stride NS).
__global__ __launch_bounds__(256) void rope_transpose(
    const bf16* __restrict__ qin, const bf16* __restrict__ kin,
    const bf16* __restrict__ sin_qt, const bf16* __restrict__ cos_qt,
    const bf16* __restrict__ sin_kt, const bf16* __restrict__ cos_kt,
    bf16* __restrict__ qr, bf16* __restrict__ kr) {
  __shared__ __align__(16) bf16 ti[32][264];  // [s][d], padded
  const int b = blockIdx.z, y = blockIdx.y, s0 = blockIdx.x * 32;
  const bool isk = (y == 8);
  const int h = isk ? 0 : y;
  const bf16* xin = isk ? kin : qin;
  const bf16* sint = isk ? sin_kt : sin_qt;
  const bf16* cost = isk ? cos_kt : cos_qt;
  const int nH = isk ? 1 : Hh;
  bf16* xout = isk ? kr : qr;
  const int tx = threadIdx.x, ty = threadIdx.y;
  const bf16* src = xin + (long)b * Ss + (long)h * Dd * NS + s0;
#pragma unroll
  for (int i = 0; i < 32; ++i) {
    int d = ty + i * 8;
    ti[tx][d] = src[(long)d * NS + tx];
  }
  __syncthreads();
  const int t = ty * 32 + tx;
  const int s = t >> 3;
  const int dpart = t & 7;
  const bf16* sp = sint + ((long)b * Ss + s0 + s) * 128;
  const bf16* cp = cost + ((long)b * Ss + s0 + s) * 128;
  bf16* dst = xout + (((long)(b * nH + h)) * Ss + s0 + s) * Dd;
#pragma unroll
  for (int i = 0; i < 4; ++i) {
    int d0 = dpart * 8 + i * 64;
    int dh = d0 & 127;
    bf16x8 a = *(const bf16x8*)&ti[s][d0];
    bf16x8 p = *(const bf16x8*)&ti[s][(d0 < 128) ? d0 + 128 : d0 - 128];
    bf16x8 sn = *(const bf16x8*)&sp[dh];
    bf16x8 cs = *(const bf16x8*)&cp[dh];
    bf16x8 o;
#pragma unroll
    for (int j = 0; j < 8; ++j) {
      float av = (float)a[j], pv = (float)p[j];
      float c = (float)cs[j], sv = (float)sn[j];
      float val = (d0 < 128) ? (av * c - pv * sv) : (av * c + pv * sv);
      o[j] = (bf16)val;
    }
    *(bf16x8*)&dst[d0] = o;
  }
}

// ---------------- GEMM 128x128: C[o][n] = sum_c A[o][c] * Bt[n][c] ---------
__global__ __launch_bounds__(256, 2) void gemm_bt(
    const bf16* __restrict__ A, const bf16* __restrict__ Bt,
    bf16* __restrict__ Cb, float* __restrict__ Cf, int M, int N, int K,
    int ntiles) {
  __shared__ __align__(16) bf16 lA[2][128 * 64];
  __shared__ __align__(16) bf16 lB[2][128 * 64];
  const int nwg = gridDim.x;
  const int cpx = nwg >> 3;                       // nwg % 8 == 0 always here
  const int bid2 = (blockIdx.x & 7) * cpx + (blockIdx.x >> 3);
  const int mt = (bid2 / ntiles) * 128, nt = (bid2 % ntiles) * 128;
  const int tid = threadIdx.x;
  const int wid = tid >> 6, lane = tid & 63;
  const int g = lane >> 4, r = lane & 15;
  const int wr = wid >> 1, wc = wid & 1;

  auto stage = [&](int buf, int kt) {
#pragma unroll
    for (int it = 0; it < 4; ++it) {
      int off = it * 4096 + tid * 16;
      int row = off >> 7;              // 128B rows (64 bf16)
      int c = (off >> 4) & 7;
      int csw = c ^ (row & 7);
      gl_lds16((const char*)(A + (long)(mt + row) * K + kt) + csw * 16,
               (char*)lA[buf] + it * 4096 + wid * 1024);
      gl_lds16((const char*)(Bt + (long)(nt + row) * K + kt) + csw * 16,
               (char*)lB[buf] + it * 4096 + wid * 1024);
    }
  };

  const f32x4 zf = {0.f, 0.f, 0.f, 0.f};
  f32x4 acc[4][4];
#pragma unroll
  for (int m = 0; m < 4; ++m)
#pragma unroll
    for (int n = 0; n < 4; ++n) acc[m][n] = zf;

  stage(0, 0);
  __syncthreads();
  int cur = 0;
  for (int kt = 0; kt < K; kt += 64) {
    if (kt + 64 < K) stage(cur ^ 1, kt + 64);
#pragma unroll
    for (int kk = 0; kk < 2; ++kk) {
      bf16x8 af[4], bfv[4];
#pragma unroll
      for (int m = 0; m < 4; ++m) {
        int row = wr * 64 + m * 16 + r;
        int csw = (kk * 4 + g) ^ (row & 7);
        af[m] = *(const bf16x8*)((const char*)lA[cur] + row * 128 + csw * 16);
      }
#pragma unroll
      for (int n = 0; n < 4; ++n) {
        int row = wc * 64 + n * 16 + r;
        int csw = (kk * 4 + g) ^ (row & 7);
        bfv[n] = *(const bf16x8*)((const char*)lB[cur] + row * 128 + csw * 16);
      }
#pragma unroll
      for (int m = 0; m < 4; ++m)
#pragma unroll
        for (int n = 0; n < 4; ++n)
          acc[m][n] = mfma16(af[m], bfv[n], acc[m][n]);
    }
    __syncthreads();
    cur ^= 1;
  }

#pragma unroll
  for (int m = 0; m < 4; ++m)
#pragma unroll
    for (int n = 0; n < 4; ++n)
#pragma unroll
      for (int e = 0; e < 4; ++e) {
        int orow = mt + wr * 64 + m * 16 + g * 4 + e;
        int col = nt + wc * 64 + n * 16 + r;
        if (Cf) {
          // out f32 [B][M][2048]: col = b*2048 + s
          long idx = (long)(col >> 11) * ((long)Cc * Ss) + (long)orow * Ss +
                     (col & 2047);
          Cf[idx] = acc[m][n][e];
        } else {
          Cb[(long)orow * N + col] = (bf16)acc[m][n][e];
        }
      }
}

// ---------------- GEMM 64x128 (small-M / KV projection) --------------------
__global__ __launch_bounds__(256, 3) void gemm_bt64(
    const bf16* __restrict__ A, const bf16* __restrict__ Bt,
    bf16* __restrict__ Cb, int M, int N, int K, int ntiles) {
  __shared__ __align__(16) bf16 lA[2][64 * 64];
  __shared__ __align__(16) bf16 lB[2][128 * 64];
  const int nwg = gridDim.x;
  const int cpx = nwg >> 3;
  const int bid2 = (blockIdx.x & 7) * cpx + (blockIdx.x >> 3);
  const int mt = (bid2 / ntiles) * 64, nt = (bid2 % ntiles) * 128;
  const int tid = threadIdx.x;
  const int wid = tid >> 6, lane = tid & 63;
  const int g = lane >> 4, r = lane & 15;
  const int wn = wid;

  auto stage = [&](int buf, int kt) {
#pragma unroll
    for (int it = 0; it < 2; ++it) {   // A tile 64x64 = 8KB
      int off = it * 4096 + tid * 16;
      int row = off >> 7;
      int c = (off >> 4) & 7;
      int csw = c ^ (row & 7);
      gl_lds16((const char*)(A + (long)(mt + row) * K + kt) + csw * 16,
               (char*)lA[buf] + it * 4096 + wid * 1024);
    }
#pragma unroll
    for (int it = 0; it < 4; ++it) {   // B tile 128x64 = 16KB
      int off = it * 4096 + tid * 16;
      int row = off >> 7;
      int c = (off >> 4) & 7;
      int csw = c ^ (row & 7);
      gl_lds16((const char*)(Bt + (long)(nt + row) * K + kt) + csw * 16,
               (char*)lB[buf] + it * 4096 + wid * 1024);
    }
  };

  const f32x4 zf = {0.f, 0.f, 0.f, 0.f};
  f32x4 acc[4][2];
#pragma unroll
  for (int m = 0; m < 4; ++m)
#pragma unroll
    for (int n = 0; n < 2; ++n) acc[m][n] = zf;

  stage(0, 0);
  __syncthreads();
  int cur = 0;
  for (int kt = 0; kt < K; kt += 64) {
    if (kt + 64 < K) stage(cur ^ 1, kt + 64);
#pragma unroll
    for (int kk = 0; kk < 2; ++kk) {
      bf16x8 af[4], bfv[2];
#pragma unroll
      for (int m = 0; m < 4; ++m) {
        int row = m * 16 + r;
        int csw = (kk * 4 + g) ^ (row & 7);
        af[m] = *(const bf16x8*)((const char*)lA[cur] + row * 128 + csw * 16);
      }
#pragma unroll
      for (int n = 0; n < 2; ++n) {
        int row = wn * 32 + n * 16 + r;
        int csw = (kk * 4 + g) ^ (row & 7);
        bfv[n] = *(const bf16x8*)((const char*)lB[cur] + row * 128 + csw * 16);
      }
#pragma unroll
      for (int m = 0; m < 4; ++m)
#pragma unroll
        for (int n = 0; n < 2; ++n)
          acc[m][n] = mfma16(af[m], bfv[n], acc[m][n]);
    }
    __syncthreads();
    cur ^= 1;
  }

#pragma unroll
  for (int m = 0; m < 4; ++m)
#pragma unroll
    for (int n = 0; n < 2; ++n)
#pragma unroll
      for (int e = 0; e < 4; ++e) {
        int orow = mt + m * 16 + g * 4 + e;
        int col = nt + wn * 32 + n * 16 + r;
        Cb[(long)orow * N + col] = (bf16)acc[m][n][e];
      }
}

// ---------------- flash attention (R11 verified, byte-identical) -----------
__global__ __launch_bounds__(256, 2) void attn_kernel(
    const bf16* __restrict__ qr, const bf16* __restrict__ kr,
    const bf16* __restrict__ kv, const float* __restrict__ mask,
    bf16* __restrict__ aout) {
  __shared__ __align__(16) bf16 lK[2][32 * 256];  // [ks][d], chunk^(row&7)
  __shared__ __align__(16) bf16 lV[2][256 * 32];  // [d][ks], chunk^((row>>1)&3)
  __shared__ __align__(16) bf16 lP[4][16 * 40];   // per-wave P[q][32+pad]
  const int b = blockIdx.z, hg = blockIdx.y;
  const int q0 = blockIdx.x * 16;
  const int tid = threadIdx.x;
  const int wid = tid >> 6, lane = tid & 63;
  const int g = lane >> 4, q = lane & 15;
  const int h = hg * 4 + wid;

  bf16x8 qf[8];
  const bf16* qp = qr + (((long)(b * Hh + h)) * Ss + q0 + q) * Dd;
#pragma unroll
  for (int kk = 0; kk < 8; ++kk) qf[kk] = *(const bf16x8*)&qp[kk * 32 + g * 8];

  const f32x4 zf = {0.f, 0.f, 0.f, 0.f};
  f32x4 oacc[16];
#pragma unroll
  for (int i = 0; i < 16; ++i) oacc[i] = zf;
  float mrun = -3e38f, lrun = 0.f;

  const char* kb = (const char*)(kr + (long)b * Ss * Dd);
  // V row d lives at kv[(256+d)*NS + b*2048 + s]
  const char* vb = (const char*)(kv + (long)256 * NS + (long)b * Ss);
  const float* mb = mask + (long)b * Ss * Ss;

  auto stage = [&](int buf, int kt) {
    const char* gK = kb + (long)kt * 512;
#pragma unroll
    for (int it = 0; it < 4; ++it) {
      int off = it * 4096 + tid * 16;
      int row = off >> 9;               // 512B rows
      int c = (off >> 4) & 31;
      int csw = c ^ (row & 7);
      gl_lds16(gK + row * 512 + csw * 16,
               (char*)lK[buf] + it * 4096 + wid * 1024);
    }
#pragma unroll
    for (int it = 0; it < 4; ++it) {
      int off = it * 4096 + tid * 16;
      int row = off >> 6;               // 64B rows
      int c = (off >> 4) & 3;
      int csw = c ^ ((row >> 1) & 3);
      gl_lds16(vb + (long)row * (NS * 2) + (long)kt * 2 + csw * 16,
               (char*)lV[buf] + it * 4096 + wid * 1024);
    }
  };

  stage(0, 0);
  __syncthreads();
  int cur = 0;

  for (int kt = 0; kt < Ss; kt += 32) {
    if (kt + 32 < Ss) stage(cur ^ 1, kt + 32);

    const float* mrow = mb + (long)(q0 + q) * Ss + kt;
    const float4 mv0 = *(const float4*)(mrow + 4 * g);
    const float4 mv1 = *(const float4*)(mrow + 16 + 4 * g);

    // QK^T swapped: sacc[n][e] = S[q][ks = 16n + 4g + e]
    f32x4 sacc[2] = {zf, zf};
    __builtin_amdgcn_s_setprio(1);
#pragma unroll
    for (int kk = 0; kk < 8; ++kk) {
#pragma unroll
      for (int n = 0; n < 2; ++n) {
        int row = n * 16 + q;
        int csw = (kk * 4 + g) ^ (row & 7);
        bf16x8 kf = *(const bf16x8*)((const char*)lK[cur] + row * 512 + csw * 16);
        sacc[n] = mfma16(kf, qf[kk], sacc[n]);
      }
    }
    __builtin_amdgcn_s_setprio(0);

    float x[8];
    x[0] = sacc[0][0] * 0.0625f + mv0.x;
    x[1] = sacc[0][1] * 0.0625f + mv0.y;
    x[2] = sacc[0][2] * 0.0625f + mv0.z;
    x[3] = sacc[0][3] * 0.0625f + mv0.w;
    x[4] = sacc[1][0] * 0.0625f + mv1.x;
    x[5] = sacc[1][1] * 0.0625f + mv1.y;
    x[6] = sacc[1][2] * 0.0625f + mv1.z;
    x[7] = sacc[1][3] * 0.0625f + mv1.w;
    float mx = fmaxf(fmaxf(fmaxf(x[0], x[1]), fmaxf(x[2], x[3])),
                     fmaxf(fmaxf(x[4], x[5]), fmaxf(x[6], x[7])));
    mx = fmaxf(mx, __shfl_xor(mx, 16, 64));
    mx = fmaxf(mx, __shfl_xor(mx, 32, 64));
    if (mx > mrun + 8.0f) {  // defer-max (T13)
      float al = __expf(mrun - mx);
      lrun *= al;
#pragma unroll
      for (int nf = 0; nf < 16; ++nf) oacc[nf] *= al;
      mrun = mx;
    }
    float p[8];
    float rs = 0.f;
#pragma unroll
    for (int i = 0; i < 8; ++i) {
      p[i] = __expf(x[i] - mrun);
      rs += p[i];
    }
    rs += __shfl_xor(rs, 16, 64);
    rs += __shfl_xor(rs, 32, 64);
    lrun += rs;

    bf16x4 w0, w1;
#pragma unroll
    for (int e = 0; e < 4; ++e) { w0[e] = (bf16)p[e]; w1[e] = (bf16)p[4 + e]; }
    *(bf16x4*)&lP[wid][q * 40 + 4 * g] = w0;
    *(bf16x4*)&lP[wid][q * 40 + 16 + 4 * g] = w1;

    bf16x8 pf = *(const bf16x8*)&lP[wid][q * 40 + g * 8];
    __builtin_amdgcn_s_setprio(1);
#pragma unroll
    for (int nf = 0; nf < 16; ++nf) {
      int row = nf * 16 + q;
      int csw = g ^ ((row >> 1) & 3);
      bf16x8 vf = *(const bf16x8*)((const char*)lV[cur] + row * 64 + csw * 16);
      oacc[nf] = mfma16(vf, pf, oacc[nf]);
    }
    __builtin_amdgcn_s_setprio(0);

    __syncthreads();
    cur ^= 1;
  }

  const float inv = 1.f / lrun;
  bf16* op = aout + ((long)(b * Ss + q0 + q)) * (Hh * Dd) + h * Dd + g * 4;
#pragma unroll
  for (int nf = 0; nf < 16; ++nf) {
    bf16x4 o4;
#pragma unroll
    for (int e = 0; e < 4; ++e) o4[e] = (bf16)(oacc[nf][e] * inv);
    *(bf16x4*)&op[nf * 16] = o4;
  }
}

// ---------------- launcher -------------------------------------------------
extern "C" void kernel_launch(void* const* d_in, const int* in_sizes, int n_in,
                              void* d_out, int out_size, void* d_ws,
                              size_t ws_size, hipStream_t stream) {
  const float* Xq = (const float*)d_in[0];
  const float* Xkv = (const float*)d_in[1];
  const float* sin_q = (const float*)d_in[2];
  const float* cos_q = (const float*)d_in[3];
  const float* sin_k = (const float*)d_in[4];
  const float* cos_k = (const float*)d_in[5];
  const float* mask = (const float*)d_in[6];
  const float* Wq = (const float*)d_in[7];
  const float* Wk = (const float*)d_in[8];
  const float* Wv = (const float*)d_in[9];
  const float* Wo = (const float*)d_in[10];
  float* out = (float*)d_out;

  char* ws = (char*)d_ws;
  const size_t MB = 1u << 20;
  bf16* Wq_bf = (bf16*)(ws + 0 * MB);
  bf16* Wo_bf = (bf16*)(ws + 8 * MB);
  bf16* Wkv_bf = (bf16*)(ws + 16 * MB);  // K rows 0..255, V rows 256..511
  bf16* sin_qt = (bf16*)(ws + 18 * MB);
  bf16* cos_qt = (bf16*)(ws + 19 * MB);
  bf16* sin_kt = (bf16*)(ws + 20 * MB);
  bf16* cos_kt = (bf16*)(ws + 21 * MB);
  bf16* Xtq = (bf16*)(ws + 22 * MB);   // [4096][2048]; reused as qr
  bf16* Xtkv = (bf16*)(ws + 38 * MB);  // [4096][2048]; reused as kr
  bf16* q_tmp = (bf16*)(ws + 54 * MB); // [2048][4096]; reused as attn out
  bf16* kv_tmp = (bf16*)(ws + 70 * MB); // [512][4096] fused K/V proj
  bf16* qr = (bf16*)(ws + 22 * MB);
  bf16* kr = (bf16*)(ws + 38 * MB);
  bf16* attnb = (bf16*)(ws + 54 * MB);

  dim3 b256(256), b32x8(32, 8);

  // all weight converts in one launch
  cvt_all<<<dim3(9216), b256, 0, stream>>>(Wq, Wo, Wk, Wv, Wq_bf, Wo_bf,
                                           Wkv_bf);

  // activations transposed to [S][*] bf16
  transpose_cvt<<<dim3(64, 64, 2), b32x8, 0, stream>>>(Xq, Xtq, Cc, Ss);
  transpose_cvt<<<dim3(64, 64, 2), b32x8, 0, stream>>>(Xkv, Xtkv, Cc, Ss);
  // all 4 sin/cos transposes in one launch
  transpose_cvt4<<<dim3(64, 16, 2), b32x8, 0, stream>>>(
      sin_q, cos_q, sin_k, cos_k, sin_qt, cos_qt, sin_kt, cos_kt, 128, Ss);

  // projections over merged N = B*S = 4096 (Bt rows are batch-contiguous)
  gemm_bt<<<dim3(512), b256, 0, stream>>>(Wq_bf, Xtq, q_tmp, nullptr,
                                          Cc, NS, Cc, NS / 128);
  gemm_bt64<<<dim3(256), b256, 0, stream>>>(Wkv_bf, Xtkv, kv_tmp,
                                            2 * Dd, NS, Cc, NS / 128);

  // RoPE + layout change for Q heads and K in one launch
  rope_transpose<<<dim3(64, 9, 2), b32x8, 0, stream>>>(
      q_tmp, kv_tmp, sin_qt, cos_qt, sin_kt, cos_kt, qr, kr);

  // attention: 4 waves = 4 heads/block, 16 q-rows, 512 blocks (2/CU)
  attn_kernel<<<dim3(128, 2, 2), b256, 0, stream>>>(qr, kr, kv_tmp, mask,
                                                    attnb);

  // output projection (f32 out, remapped to [B][hidden][S])
  gemm_bt<<<dim3(512), b256, 0, stream>>>(Wo_bf, attnb, nullptr, out,
                                          Cc, NS, Cc, NS / 128);
}